// Round 1
// baseline (431.812 us; speedup 1.0000x reference)
//
#include <hip/hip_runtime.h>

#define N_COLS 4096
#define BLOCK 256
#define EPS 1e-7f
#define NEG_BIG -3.402823466e+38f

// compare-exchange keeping the LARGER value in `a` (descending order)
__device__ __forceinline__ void cswap_desc(float& a, float& b) {
    float hi = fmaxf(a, b);
    float lo = fminf(a, b);
    a = hi;
    b = lo;
}

// Predicated insert of v into sorted-descending a[8] (drops the smallest).
__device__ __forceinline__ void insert8(float a[8], float v) {
#pragma unroll
    for (int j = 0; j < 8; ++j) {
        float hi = fmaxf(a[j], v);
        float lo = fminf(a[j], v);
        a[j] = hi;
        v = lo;
    }
}

// Merge sorted-desc b[8] into sorted-desc a[8], keeping the top-8 (sorted desc).
// Bitonic split: t[i] = max(a[i], b[7-i]) holds the 8 largest as a bitonic
// sequence; then a 3-stage bitonic merge network (dist 4,2,1) sorts it desc.
__device__ __forceinline__ void merge8(float a[8], const float b[8]) {
    float t[8];
#pragma unroll
    for (int i = 0; i < 8; ++i) t[i] = fmaxf(a[i], b[7 - i]);
    // dist 4
    cswap_desc(t[0], t[4]);
    cswap_desc(t[1], t[5]);
    cswap_desc(t[2], t[6]);
    cswap_desc(t[3], t[7]);
    // dist 2
    cswap_desc(t[0], t[2]);
    cswap_desc(t[1], t[3]);
    cswap_desc(t[4], t[6]);
    cswap_desc(t[5], t[7]);
    // dist 1
    cswap_desc(t[0], t[1]);
    cswap_desc(t[2], t[3]);
    cswap_desc(t[4], t[5]);
    cswap_desc(t[6], t[7]);
#pragma unroll
    for (int i = 0; i < 8; ++i) a[i] = t[i];
}

__global__ __launch_bounds__(BLOCK) void sparse_attn_topk_kernel(
    const float* __restrict__ in, float* __restrict__ out) {
    const int row  = blockIdx.x;
    const int tid  = threadIdx.x;   // 0..255
    const int lane = tid & 63;
    const int wave = tid >> 6;      // 0..3

    const size_t base = (size_t)row * N_COLS;
    const float4* in4 = reinterpret_cast<const float4*>(in + base);
    float4* out4      = reinterpret_cast<float4*>(out + base);

    // ---- single read pass: 16 floats/thread, coalesced float4 ----
    float x[16];
#pragma unroll
    for (int k = 0; k < 4; ++k) {
        float4 v = in4[tid + k * BLOCK];
        x[k * 4 + 0] = v.x;
        x[k * 4 + 1] = v.y;
        x[k * 4 + 2] = v.z;
        x[k * 4 + 3] = v.w;
    }

    // ---- per-thread top-8 (sorted desc) ----
    float a[8];
#pragma unroll
    for (int i = 0; i < 8; ++i) a[i] = NEG_BIG;
#pragma unroll
    for (int i = 0; i < 16; ++i) insert8(a, x[i]);

    // ---- wave-level butterfly merge: all 64 lanes end with wave top-8 ----
#pragma unroll
    for (int d = 1; d < 64; d <<= 1) {
        float b[8];
#pragma unroll
        for (int i = 0; i < 8; ++i) b[i] = __shfl_xor(a[i], d, 64);
        merge8(a, b);
    }

    // ---- cross-wave merge via LDS (4 waves) ----
    __shared__ float s_top[4][8];
    __shared__ float s_sum[4];
    if (lane == 0) {
#pragma unroll
        for (int i = 0; i < 8; ++i) s_top[wave][i] = a[i];
    }
    __syncthreads();
#pragma unroll
    for (int w = 0; w < 4; ++w) {
        if (w != wave) {  // wave-uniform branch
            float b[8];
#pragma unroll
            for (int i = 0; i < 8; ++i) b[i] = s_top[w][i];
            merge8(a, b);
        }
    }
    const float delta = a[7] + EPS;  // 8th largest + eps

    // ---- sum of clipped values ----
    float ps = 0.0f;
#pragma unroll
    for (int i = 0; i < 16; ++i) ps += fmaxf(x[i] - delta, 0.0f);
#pragma unroll
    for (int d = 1; d < 64; d <<= 1) ps += __shfl_xor(ps, d, 64);
    if (lane == 0) s_sum[wave] = ps;
    __syncthreads();
    const float total = s_sum[0] + s_sum[1] + s_sum[2] + s_sum[3];
    const float inv   = 1.0f / (total + EPS);

    // ---- single write pass ----
#pragma unroll
    for (int k = 0; k < 4; ++k) {
        float4 o;
        o.x = fmaxf(x[k * 4 + 0] - delta, 0.0f) * inv;
        o.y = fmaxf(x[k * 4 + 1] - delta, 0.0f) * inv;
        o.z = fmaxf(x[k * 4 + 2] - delta, 0.0f) * inv;
        o.w = fmaxf(x[k * 4 + 3] - delta, 0.0f) * inv;
        out4[tid + k * BLOCK] = o;
    }
}

extern "C" void kernel_launch(void* const* d_in, const int* in_sizes, int n_in,
                              void* d_out, int out_size, void* d_ws, size_t ws_size,
                              hipStream_t stream) {
    const float* attn_s = (const float*)d_in[0];
    float* out = (float*)d_out;
    const int n_rows = in_sizes[0] / N_COLS;  // 16384
    sparse_attn_topk_kernel<<<n_rows, BLOCK, 0, stream>>>(attn_s, out);
}